// Round 4
// baseline (154113.843 us; speedup 1.0000x reference)
//
#include <hip/hip_runtime.h>
#include <hip/hip_bf16.h>
#include <math.h>

#define EPSV 1e-5f
#define BDIM 32
#define TSTEPS 2048
#define DIN 256
#define HDIM 512
#define H2 1024
#define H3 1536

#define NG 8      // chain groups (one per XCD via blockIdx%8 round-robin)
#define CPG 4     // chains per group
#define BPG 16    // blocks per group
#define ZRC 64    // zr cols per block  (16*64 = 1024)
#define HCC 32    // h-cand cols per block (16*32 = 512)

// ---------------- fp32 tiled GEMM: C = A(MxK) @ B(KxN) (+bias) ----------------
template <int BM, int BN, int BK, int TM, int TN>
__global__ __launch_bounds__(256) void sgemm(const float* __restrict__ A,
                                             const float* __restrict__ B,
                                             const float* __restrict__ bias,
                                             float* __restrict__ C,
                                             int M, int N, int K) {
    __shared__ float As[BK][BM + 4];
    __shared__ float Bs[BK][BN + 4];

    const int tid = threadIdx.x;
    const int bm = blockIdx.y * BM;
    const int bn = blockIdx.x * BN;

    const int tr = (tid >> 4) * TM;
    const int tc = (tid & 15) * TN;

    float acc[TM][TN];
#pragma unroll
    for (int i = 0; i < TM; ++i)
#pragma unroll
        for (int j = 0; j < TN; ++j) acc[i][j] = 0.f;

    for (int k0 = 0; k0 < K; k0 += BK) {
#pragma unroll
        for (int r = 0; r < 2; ++r) {
            int f = tid + r * 256;
            int arow = f >> 2;
            int acol = (f & 3) * 4;
            float4 v = *(const float4*)&A[(size_t)(bm + arow) * K + k0 + acol];
            As[acol + 0][arow] = v.x;
            As[acol + 1][arow] = v.y;
            As[acol + 2][arow] = v.z;
            As[acol + 3][arow] = v.w;
        }
#pragma unroll
        for (int r = 0; r < 2; ++r) {
            int f = tid + r * 256;
            int brow = f >> 5;
            int bcol = (f & 31) * 4;
            float4 v = *(const float4*)&B[(size_t)(k0 + brow) * N + bn + bcol];
            *(float4*)&Bs[brow][bcol] = v;
        }
        __syncthreads();
#pragma unroll
        for (int k = 0; k < BK; ++k) {
            float a[TM], b[TN];
            float4 a0 = *(const float4*)&As[k][tr];
            float4 a1 = *(const float4*)&As[k][tr + 4];
            a[0] = a0.x; a[1] = a0.y; a[2] = a0.z; a[3] = a0.w;
            a[4] = a1.x; a[5] = a1.y; a[6] = a1.z; a[7] = a1.w;
            float4 b0 = *(const float4*)&Bs[k][tc];
            float4 b1 = *(const float4*)&Bs[k][tc + 4];
            b[0] = b0.x; b[1] = b0.y; b[2] = b0.z; b[3] = b0.w;
            b[4] = b1.x; b[5] = b1.y; b[6] = b1.z; b[7] = b1.w;
#pragma unroll
            for (int i = 0; i < TM; ++i)
#pragma unroll
                for (int j = 0; j < TN; ++j) acc[i][j] += a[i] * b[j];
        }
        __syncthreads();
    }

#pragma unroll
    for (int i = 0; i < TM; ++i) {
        size_t row = (size_t)(bm + tr + i) * N + bn + tc;
#pragma unroll
        for (int j = 0; j < TN; j += 4) {
            float4 o;
            o.x = acc[i][j + 0];
            o.y = acc[i][j + 1];
            o.z = acc[i][j + 2];
            o.w = acc[i][j + 3];
            if (bias) {
                o.x += bias[bn + tc + j + 0];
                o.y += bias[bn + tc + j + 1];
                o.z += bias[bn + tc + j + 2];
                o.w += bias[bn + tc + j + 3];
            }
            *(float4*)&C[row + j] = o;
        }
    }
}

// ---------------- block-wide {sum, sumsq} reduction (256 threads) -------------
__device__ __forceinline__ void block_reduce2(float& a, float& b, float* red) {
#pragma unroll
    for (int off = 32; off > 0; off >>= 1) {
        a += __shfl_down(a, off);
        b += __shfl_down(b, off);
    }
    const int wid = threadIdx.x >> 6;
    __syncthreads();
    if ((threadIdx.x & 63) == 0) {
        red[wid] = a;
        red[4 + wid] = b;
    }
    __syncthreads();
    a = red[0] + red[1] + red[2] + red[3];
    b = red[4] + red[5] + red[6] + red[7];
}

// ---------------- LN0: in-place layernorm of s1 rows (+bias b) ----------------
__global__ __launch_bounds__(256) void ln0_kernel(float* __restrict__ s1,
                                                  const float* __restrict__ bvec,
                                                  const float* __restrict__ g0,
                                                  const float* __restrict__ b0) {
    const size_t row = blockIdx.x;
    float* p = s1 + row * H3;
    const int tid = threadIdx.x;
    __shared__ float red[8];
    float v[6];
    float sum = 0.f, ssq = 0.f;
#pragma unroll
    for (int j = 0; j < 6; ++j) {
        int k = tid + 256 * j;
        float x = p[k] + bvec[k];
        v[j] = x;
        sum += x;
        ssq += x * x;
    }
    block_reduce2(sum, ssq, red);
    float m = sum * (1.f / H3);
    float var = fmaxf(ssq * (1.f / H3) - m * m, 0.f);
    float inv = 1.f / (sqrtf(var + EPSV) + EPSV);
#pragma unroll
    for (int j = 0; j < 6; ++j) {
        int k = tid + 256 * j;
        p[k] = g0[k] * ((v[j] - m) * inv) + b0[k];
    }
}

// ------------- XCD-local per-block-flag barrier (16 participants) -------------
// flags: one 128B line (32 uints) per block of the group. Monotonic epochs.
__device__ __forceinline__ void xbar(unsigned int* gflag, int b, unsigned int ep) {
    __threadfence();          // publish stores visible at agent scope
    __syncthreads();
    if (threadIdx.x == 0)
        __hip_atomic_store(gflag + b * 32, ep, __ATOMIC_RELEASE,
                           __HIP_MEMORY_SCOPE_AGENT);
    if (threadIdx.x < BPG) {
        while (__hip_atomic_load(gflag + threadIdx.x * 32, __ATOMIC_ACQUIRE,
                                 __HIP_MEMORY_SCOPE_AGENT) < ep)
            __builtin_amdgcn_s_sleep(1);
    }
    __syncthreads();
}

// ---------------- persistent col-split recurrent scan (XCD-local) -------------
// 128 blocks x 1024 thr. group g = blockIdx%8 (one per XCD), b = blockIdx/8.
// Block b owns zr cols [64b,64b+64) and h-cand cols [1024+32b,+32).
// Full h-update is REPLICATED per block (h never published; 2 barriers/step).
__global__ __launch_bounds__(1024) void scan_kernel(
    const float* __restrict__ s1,    // (32,2048,1536) pre-LN'd
    const float* __restrict__ U,     // (512,1536)
    const float* __restrict__ gam,   // (2,1536)
    const float* __restrict__ bet,   // (2,1536)
    const int* __restrict__ mask,    // (32,2048)
    float* __restrict__ out,         // (32,2048,512)
    float* __restrict__ s2z,         // (32,1024) publish
    float* __restrict__ s2h,         // (32,512)  publish
    unsigned int* __restrict__ flags)
{
    const int g = blockIdx.x & 7;
    const int b = blockIdx.x >> 3;
    const int t = threadIdx.x;
    const int wav = t >> 6;
    const int lane = t & 63;

    // chain-major LDS: row ch, 512 cols -> consecutive-word / broadcast access
    __shared__ float hT[CPG][HDIM];
    __shared__ float rhT[CPG][HDIM];
    __shared__ float zT[CPG][HDIM];
    __shared__ float part[16][256];
    __shared__ float red[CPG][8];

    for (int i = t; i < CPG * HDIM; i += 1024) (&hT[0][0])[i] = 0.f;
    __syncthreads();

    const float* g1 = gam + H3;
    const float* b1 = bet + H3;
    unsigned int* gflag = flags + g * BPG * 32;

    // GEMV-A roles: 16 col-quads x 64 K-splits (K strided: k = kA + 64*kk)
    const int cA = t & 15;
    const int kA = t >> 4;
    // GEMV-B roles: 8 col-quads x 128 K-splits (k = kB + 128*kk)
    const int cB = t & 7;
    const int kB = t >> 3;
    // elementwise roles: 4 chains x 256 threads
    const int ch = t >> 8;
    const int lc = t & 255;
    const int gch = g * CPG + ch;

    const float* s1c = s1 + (size_t)gch * TSTEPS * H3;
    const int* mrow = mask + gch * TSTEPS;
    const float* s2zc = s2z + (size_t)gch * H2;
    const float* s2hc = s2h + (size_t)gch * HDIM;

    const float* UA = U + (size_t)kA * H3 + ZRC * b + 4 * cA;
    const float* UB = U + (size_t)kB * H3 + H2 + HCC * b + 4 * cB;

    unsigned int ep = 0;

    for (int step = 0; step < TSTEPS; ++step) {
        // ---- prefetch this step's s1 slice + mask (hidden under GEMV-A) ----
        const float* s1p = s1c + (size_t)step * H3;
        float s1z[4], s1h[2];
#pragma unroll
        for (int j = 0; j < 4; ++j) s1z[j] = s1p[lc + 256 * j];
#pragma unroll
        for (int j = 0; j < 2; ++j) s1h[j] = s1p[H2 + lc + 256 * j];
        const int mk = mrow[step];

        // ---- GEMV-A: h @ U[:, 64b..64b+64) for 4 chains ----
        float4 acc[CPG];
#pragma unroll
        for (int c = 0; c < CPG; ++c) acc[c] = make_float4(0.f, 0.f, 0.f, 0.f);
#pragma unroll
        for (int kk = 0; kk < 8; ++kk) {
            const int k = kA + 64 * kk;
            float4 u = *(const float4*)(UA + (size_t)(64 * kk) * H3);
            float h0 = hT[0][k], h1 = hT[1][k], h2 = hT[2][k], h3 = hT[3][k];
            acc[0].x += h0 * u.x; acc[0].y += h0 * u.y; acc[0].z += h0 * u.z; acc[0].w += h0 * u.w;
            acc[1].x += h1 * u.x; acc[1].y += h1 * u.y; acc[1].z += h1 * u.z; acc[1].w += h1 * u.w;
            acc[2].x += h2 * u.x; acc[2].y += h2 * u.y; acc[2].z += h2 * u.z; acc[2].w += h2 * u.w;
            acc[3].x += h3 * u.x; acc[3].y += h3 * u.y; acc[3].z += h3 * u.z; acc[3].w += h3 * u.w;
        }
        // reduce 4 K-slices within wave (lane bits 4,5)
#pragma unroll
        for (int off = 16; off <= 32; off <<= 1) {
#pragma unroll
            for (int c = 0; c < CPG; ++c) {
                acc[c].x += __shfl_xor(acc[c].x, off);
                acc[c].y += __shfl_xor(acc[c].y, off);
                acc[c].z += __shfl_xor(acc[c].z, off);
                acc[c].w += __shfl_xor(acc[c].w, off);
            }
        }
        if (lane < 16) {
#pragma unroll
            for (int c = 0; c < CPG; ++c)
                *(float4*)&part[wav][c * 64 + 4 * lane] = acc[c];
        }
        __syncthreads();
        if (t < 256) {  // t = ch*64 + col
            float s = 0.f;
#pragma unroll
            for (int w = 0; w < 16; ++w) s += part[w][t];
            s2z[(size_t)(g * CPG + (t >> 6)) * H2 + ZRC * b + (t & 63)] = s;
        }
        xbar(gflag, b, ++ep);

        // ---- LN stats over full zr row + sigmoid; z full, rh full (replicated) ----
        float vz[4];
        float sum = 0.f, ssq = 0.f;
#pragma unroll
        for (int j = 0; j < 4; ++j) {
            float v = s2zc[lc + 256 * j];
            vz[j] = v;
            sum += v;
            ssq += v * v;
        }
#pragma unroll
        for (int off = 1; off < 64; off <<= 1) {
            sum += __shfl_xor(sum, off);
            ssq += __shfl_xor(ssq, off);
        }
        if (lane == 0) {
            red[ch][2 * (wav & 3) + 0] = sum;
            red[ch][2 * (wav & 3) + 1] = ssq;
        }
        __syncthreads();
        {
            float sm = red[ch][0] + red[ch][2] + red[ch][4] + red[ch][6];
            float sq = red[ch][1] + red[ch][3] + red[ch][5] + red[ch][7];
            float m1 = sm * (1.f / H2);
            float var1 = fmaxf(sq * (1.f / H2) - m1 * m1, 0.f);
            float inv1 = 1.f / (sqrtf(var1 + EPSV) + EPSV);
#pragma unroll
            for (int j = 0; j < 4; ++j) {
                int c = lc + 256 * j;
                float s2ln = g1[c] * ((vz[j] - m1) * inv1) + b1[c];
                float pre = s1z[j] + s2ln;
                float sg = fminf(fmaxf(0.2f * pre + 0.5f, 0.f), 1.f);
                if (c < HDIM)
                    zT[ch][c] = sg;
                else
                    rhT[ch][c - HDIM] = sg * hT[ch][c - HDIM];
            }
        }
        __syncthreads();

        // ---- GEMV-B: (r*h) @ U[:, 1024+32b..+32) for 4 chains ----
        float4 accB[CPG];
#pragma unroll
        for (int c = 0; c < CPG; ++c) accB[c] = make_float4(0.f, 0.f, 0.f, 0.f);
#pragma unroll
        for (int kk = 0; kk < 4; ++kk) {
            const int k = kB + 128 * kk;
            float4 u = *(const float4*)(UB + (size_t)(128 * kk) * H3);
            float r0 = rhT[0][k], r1 = rhT[1][k], r2 = rhT[2][k], r3 = rhT[3][k];
            accB[0].x += r0 * u.x; accB[0].y += r0 * u.y; accB[0].z += r0 * u.z; accB[0].w += r0 * u.w;
            accB[1].x += r1 * u.x; accB[1].y += r1 * u.y; accB[1].z += r1 * u.z; accB[1].w += r1 * u.w;
            accB[2].x += r2 * u.x; accB[2].y += r2 * u.y; accB[2].z += r2 * u.z; accB[2].w += r2 * u.w;
            accB[3].x += r3 * u.x; accB[3].y += r3 * u.y; accB[3].z += r3 * u.z; accB[3].w += r3 * u.w;
        }
#pragma unroll
        for (int off = 8; off <= 32; off <<= 1) {
#pragma unroll
            for (int c = 0; c < CPG; ++c) {
                accB[c].x += __shfl_xor(accB[c].x, off);
                accB[c].y += __shfl_xor(accB[c].y, off);
                accB[c].z += __shfl_xor(accB[c].z, off);
                accB[c].w += __shfl_xor(accB[c].w, off);
            }
        }
        if (lane < 8) {
#pragma unroll
            for (int c = 0; c < CPG; ++c)
                *(float4*)&part[wav][c * 32 + 4 * lane] = accB[c];
        }
        __syncthreads();
        if (t < 128) {  // t = ch*32 + col
            float s = 0.f;
#pragma unroll
            for (int w = 0; w < 16; ++w) s += part[w][t];
            s2h[(size_t)(g * CPG + (t >> 5)) * HDIM + HCC * b + (t & 31)] = s;
        }
        xbar(gflag, b, ++ep);

        // ---- LN stats over h-cand row + tanh + FULL replicated h update ----
        float vh[2];
        float sum2 = 0.f, ssq2 = 0.f;
#pragma unroll
        for (int j = 0; j < 2; ++j) {
            float v = s2hc[lc + 256 * j];
            vh[j] = v;
            sum2 += v;
            ssq2 += v * v;
        }
#pragma unroll
        for (int off = 1; off < 64; off <<= 1) {
            sum2 += __shfl_xor(sum2, off);
            ssq2 += __shfl_xor(ssq2, off);
        }
        if (lane == 0) {
            red[ch][2 * (wav & 3) + 0] = sum2;
            red[ch][2 * (wav & 3) + 1] = ssq2;
        }
        __syncthreads();
        {
            float sm = red[ch][0] + red[ch][2] + red[ch][4] + red[ch][6];
            float sq = red[ch][1] + red[ch][3] + red[ch][5] + red[ch][7];
            float m2 = sm * (1.f / HDIM);
            float var2 = fmaxf(sq * (1.f / HDIM) - m2 * m2, 0.f);
            float inv2 = 1.f / (sqrtf(var2 + EPSV) + EPSV);
#pragma unroll
            for (int j = 0; j < 2; ++j) {
                int c = lc + 256 * j;
                float ln = g1[H2 + c] * ((vh[j] - m2) * inv2) + b1[H2 + c];
                float hc = tanhf(s1h[j] + ln);
                float hp = hT[ch][c];
                float z = zT[ch][c];
                float h_ = z * hp + (1.f - z) * hc;
                float hn = mk ? h_ : hp;
                hT[ch][c] = hn;
                if ((c >> 5) == b)  // own 32-col slice -> contiguous 128B burst
                    out[((size_t)gch * TSTEPS + step) * HDIM + c] = hn;
            }
        }
        __syncthreads();  // hT complete before next step's GEMV-A
    }
}

extern "C" void kernel_launch(void* const* d_in, const int* in_sizes, int n_in,
                              void* d_out, int out_size, void* d_ws, size_t ws_size,
                              hipStream_t stream) {
    const float* x      = (const float*)d_in[0];
    const int*   mask   = (const int*)d_in[1];
    const float* W_emb  = (const float*)d_in[2];
    const float* b_emb  = (const float*)d_in[3];
    const float* W      = (const float*)d_in[4];
    const float* U      = (const float*)d_in[5];
    const float* bias   = (const float*)d_in[6];
    const float* gammas = (const float*)d_in[7];
    const float* betas  = (const float*)d_in[8];
    float* out = (float*)d_out;

    const int M = BDIM * TSTEPS;  // 65536
    float* x_emb = (float*)d_ws;              // M x 512  (128 MB)
    float* s1    = x_emb + (size_t)M * HDIM;  // M x 1536 (384 MB)

    // scratch overlaid in x_emb region (dead after GEMM2)
    float* s2z = x_emb;                                     // 32x1024
    float* s2h = s2z + 32 * H2;                             // 32x512
    unsigned int* flags = (unsigned int*)(s2h + 32 * HDIM); // 128 x 32 uints

    // x_emb = x @ W_emb + b_emb
    sgemm<128, 128, 16, 8, 8><<<dim3(HDIM / 128, M / 128), 256, 0, stream>>>(
        x, W_emb, b_emb, x_emb, M, HDIM, DIN);
    // s1 = x_emb @ W  (raw)
    sgemm<128, 128, 16, 8, 8><<<dim3(H3 / 128, M / 128), 256, 0, stream>>>(
        x_emb, W, nullptr, s1, M, H3, HDIM);
    // s1 = LN0(s1 + bias) with gammas[0]/betas[0]  (h-independent, hoisted)
    ln0_kernel<<<M, 256, 0, stream>>>(s1, bias, gammas, betas);
    // zero barrier flags (ws re-poisoned 0xAA before every timed launch)
    hipMemsetAsync(flags, 0, NG * BPG * 32 * sizeof(unsigned int), stream);
    // persistent XCD-local col-split scan
    scan_kernel<<<NG * BPG, 1024, 0, stream>>>(s1, U, gammas, betas, mask, out,
                                               s2z, s2h, flags);
}

// Round 5
// 30714.008 us; speedup vs baseline: 5.0177x; 5.0177x over previous
//
#include <hip/hip_runtime.h>
#include <hip/hip_bf16.h>
#include <math.h>

#define EPSV 1e-5f
#define BDIM 32
#define TSTEPS 2048
#define DIN 256
#define HDIM 512
#define H2 1024
#define H3 1536

#define NG 8      // chain groups
#define CPG 4     // chains per group
#define BPG 16    // blocks per group
#define ZRC 64    // zr cols per block  (16*64 = 1024)
#define HCC 32    // h-cand cols per block (16*32 = 512)

// sc1 message-passing helpers: per-access agent coherence, NO cache flushes.
__device__ __forceinline__ void msg_store(float* p, float v) {
    __hip_atomic_store(p, v, __ATOMIC_RELAXED, __HIP_MEMORY_SCOPE_AGENT);
}
__device__ __forceinline__ float msg_load(const float* p) {
    return __hip_atomic_load(p, __ATOMIC_RELAXED, __HIP_MEMORY_SCOPE_AGENT);
}

// ---------------- fp32 tiled GEMM: C = A(MxK) @ B(KxN) (+bias) ----------------
template <int BM, int BN, int BK, int TM, int TN>
__global__ __launch_bounds__(256) void sgemm(const float* __restrict__ A,
                                             const float* __restrict__ B,
                                             const float* __restrict__ bias,
                                             float* __restrict__ C,
                                             int M, int N, int K) {
    __shared__ float As[BK][BM + 4];
    __shared__ float Bs[BK][BN + 4];

    const int tid = threadIdx.x;
    const int bm = blockIdx.y * BM;
    const int bn = blockIdx.x * BN;

    const int tr = (tid >> 4) * TM;
    const int tc = (tid & 15) * TN;

    float acc[TM][TN];
#pragma unroll
    for (int i = 0; i < TM; ++i)
#pragma unroll
        for (int j = 0; j < TN; ++j) acc[i][j] = 0.f;

    for (int k0 = 0; k0 < K; k0 += BK) {
#pragma unroll
        for (int r = 0; r < 2; ++r) {
            int f = tid + r * 256;
            int arow = f >> 2;
            int acol = (f & 3) * 4;
            float4 v = *(const float4*)&A[(size_t)(bm + arow) * K + k0 + acol];
            As[acol + 0][arow] = v.x;
            As[acol + 1][arow] = v.y;
            As[acol + 2][arow] = v.z;
            As[acol + 3][arow] = v.w;
        }
#pragma unroll
        for (int r = 0; r < 2; ++r) {
            int f = tid + r * 256;
            int brow = f >> 5;
            int bcol = (f & 31) * 4;
            float4 v = *(const float4*)&B[(size_t)(k0 + brow) * N + bn + bcol];
            *(float4*)&Bs[brow][bcol] = v;
        }
        __syncthreads();
#pragma unroll
        for (int k = 0; k < BK; ++k) {
            float a[TM], b[TN];
            float4 a0 = *(const float4*)&As[k][tr];
            float4 a1 = *(const float4*)&As[k][tr + 4];
            a[0] = a0.x; a[1] = a0.y; a[2] = a0.z; a[3] = a0.w;
            a[4] = a1.x; a[5] = a1.y; a[6] = a1.z; a[7] = a1.w;
            float4 b0 = *(const float4*)&Bs[k][tc];
            float4 b1 = *(const float4*)&Bs[k][tc + 4];
            b[0] = b0.x; b[1] = b0.y; b[2] = b0.z; b[3] = b0.w;
            b[4] = b1.x; b[5] = b1.y; b[6] = b1.z; b[7] = b1.w;
#pragma unroll
            for (int i = 0; i < TM; ++i)
#pragma unroll
                for (int j = 0; j < TN; ++j) acc[i][j] += a[i] * b[j];
        }
        __syncthreads();
    }

#pragma unroll
    for (int i = 0; i < TM; ++i) {
        size_t row = (size_t)(bm + tr + i) * N + bn + tc;
#pragma unroll
        for (int j = 0; j < TN; j += 4) {
            float4 o;
            o.x = acc[i][j + 0];
            o.y = acc[i][j + 1];
            o.z = acc[i][j + 2];
            o.w = acc[i][j + 3];
            if (bias) {
                o.x += bias[bn + tc + j + 0];
                o.y += bias[bn + tc + j + 1];
                o.z += bias[bn + tc + j + 2];
                o.w += bias[bn + tc + j + 3];
            }
            *(float4*)&C[row + j] = o;
        }
    }
}

// ---------------- block-wide {sum, sumsq} reduction (256 threads) -------------
__device__ __forceinline__ void block_reduce2(float& a, float& b, float* red) {
#pragma unroll
    for (int off = 32; off > 0; off >>= 1) {
        a += __shfl_down(a, off);
        b += __shfl_down(b, off);
    }
    const int wid = threadIdx.x >> 6;
    __syncthreads();
    if ((threadIdx.x & 63) == 0) {
        red[wid] = a;
        red[4 + wid] = b;
    }
    __syncthreads();
    a = red[0] + red[1] + red[2] + red[3];
    b = red[4] + red[5] + red[6] + red[7];
}

// ---------------- LN0: in-place layernorm of s1 rows (+bias b) ----------------
__global__ __launch_bounds__(256) void ln0_kernel(float* __restrict__ s1,
                                                  const float* __restrict__ bvec,
                                                  const float* __restrict__ g0,
                                                  const float* __restrict__ b0) {
    const size_t row = blockIdx.x;
    float* p = s1 + row * H3;
    const int tid = threadIdx.x;
    __shared__ float red[8];
    float v[6];
    float sum = 0.f, ssq = 0.f;
#pragma unroll
    for (int j = 0; j < 6; ++j) {
        int k = tid + 256 * j;
        float x = p[k] + bvec[k];
        v[j] = x;
        sum += x;
        ssq += x * x;
    }
    block_reduce2(sum, ssq, red);
    float m = sum * (1.f / H3);
    float var = fmaxf(ssq * (1.f / H3) - m * m, 0.f);
    float inv = 1.f / (sqrtf(var + EPSV) + EPSV);
#pragma unroll
    for (int j = 0; j < 6; ++j) {
        int k = tid + 256 * j;
        p[k] = g0[k] * ((v[j] - m) * inv) + b0[k];
    }
}

// ------------- fence-free flag barrier (16 participants, sc1 relaxed) ---------
// flags: one 128B line (32 uints) per block of the group. Monotonic epochs.
// NO acquire/release: sc1 data stores are drained (vmcnt0) before the flag
// store; polls are relaxed sc1 loads -> no buffer_inv/wbl2 L2 flush storms.
__device__ __forceinline__ void xbar(unsigned int* gflag, int b, unsigned int ep) {
    asm volatile("s_waitcnt vmcnt(0)" ::: "memory");  // this wave's sc1 stores visible
    __syncthreads();                                  // all waves' stores drained
    if (threadIdx.x == 0)
        __hip_atomic_store(gflag + b * 32, ep, __ATOMIC_RELAXED,
                           __HIP_MEMORY_SCOPE_AGENT);
    if (threadIdx.x < BPG) {
        while (__hip_atomic_load(gflag + threadIdx.x * 32, __ATOMIC_RELAXED,
                                 __HIP_MEMORY_SCOPE_AGENT) < ep)
            __builtin_amdgcn_s_sleep(1);
    }
    asm volatile("" ::: "memory");  // don't hoist data loads above the spin
    __syncthreads();
}

// ---------------- persistent col-split recurrent scan -------------------------
// 128 blocks x 1024 thr. group g = blockIdx%8, b = blockIdx/8.
// Block b owns zr cols [64b,64b+64) and h-cand cols [1024+32b,+32).
// Full h-update is REPLICATED per block (h never published; 2 barriers/step).
// All cross-block payloads (s2z, s2h) use sc1 relaxed atomics (agent scope).
__global__ __launch_bounds__(1024) void scan_kernel(
    const float* __restrict__ s1,    // (32,2048,1536) pre-LN'd
    const float* __restrict__ U,     // (512,1536)
    const float* __restrict__ gam,   // (2,1536)
    const float* __restrict__ bet,   // (2,1536)
    const int* __restrict__ mask,    // (32,2048)
    float* __restrict__ out,         // (32,2048,512)
    float* __restrict__ s2z,         // (32,1024) publish
    float* __restrict__ s2h,         // (32,512)  publish
    unsigned int* __restrict__ flags)
{
    const int g = blockIdx.x & 7;
    const int b = blockIdx.x >> 3;
    const int t = threadIdx.x;
    const int wav = t >> 6;
    const int lane = t & 63;

    // chain-major LDS: row ch, 512 cols -> consecutive-word / broadcast access
    __shared__ float hT[CPG][HDIM];
    __shared__ float rhT[CPG][HDIM];
    __shared__ float zT[CPG][HDIM];
    __shared__ float part[16][256];
    __shared__ float red[CPG][8];

    for (int i = t; i < CPG * HDIM; i += 1024) (&hT[0][0])[i] = 0.f;
    __syncthreads();

    const float* g1 = gam + H3;
    const float* b1 = bet + H3;
    unsigned int* gflag = flags + g * BPG * 32;

    // GEMV-A roles: 16 col-quads x 64 K-splits (K strided: k = kA + 64*kk)
    const int cA = t & 15;
    const int kA = t >> 4;
    // GEMV-B roles: 8 col-quads x 128 K-splits (k = kB + 128*kk)
    const int cB = t & 7;
    const int kB = t >> 3;
    // elementwise roles: 4 chains x 256 threads
    const int ch = t >> 8;
    const int lc = t & 255;
    const int gch = g * CPG + ch;

    const float* s1c = s1 + (size_t)gch * TSTEPS * H3;
    const int* mrow = mask + gch * TSTEPS;
    const float* s2zc = s2z + (size_t)gch * H2;
    const float* s2hc = s2h + (size_t)gch * HDIM;

    const float* UA = U + (size_t)kA * H3 + ZRC * b + 4 * cA;
    const float* UB = U + (size_t)kB * H3 + H2 + HCC * b + 4 * cB;

    unsigned int ep = 0;

    for (int step = 0; step < TSTEPS; ++step) {
        // ---- prefetch this step's s1 slice + mask (hidden under GEMV-A) ----
        const float* s1p = s1c + (size_t)step * H3;
        float s1z[4], s1h[2];
#pragma unroll
        for (int j = 0; j < 4; ++j) s1z[j] = s1p[lc + 256 * j];
#pragma unroll
        for (int j = 0; j < 2; ++j) s1h[j] = s1p[H2 + lc + 256 * j];
        const int mk = mrow[step];

        // ---- GEMV-A: h @ U[:, 64b..64b+64) for 4 chains ----
        float4 acc[CPG];
#pragma unroll
        for (int c = 0; c < CPG; ++c) acc[c] = make_float4(0.f, 0.f, 0.f, 0.f);
#pragma unroll
        for (int kk = 0; kk < 8; ++kk) {
            const int k = kA + 64 * kk;
            float4 u = *(const float4*)(UA + (size_t)(64 * kk) * H3);
            float h0 = hT[0][k], h1 = hT[1][k], h2 = hT[2][k], h3 = hT[3][k];
            acc[0].x += h0 * u.x; acc[0].y += h0 * u.y; acc[0].z += h0 * u.z; acc[0].w += h0 * u.w;
            acc[1].x += h1 * u.x; acc[1].y += h1 * u.y; acc[1].z += h1 * u.z; acc[1].w += h1 * u.w;
            acc[2].x += h2 * u.x; acc[2].y += h2 * u.y; acc[2].z += h2 * u.z; acc[2].w += h2 * u.w;
            acc[3].x += h3 * u.x; acc[3].y += h3 * u.y; acc[3].z += h3 * u.z; acc[3].w += h3 * u.w;
        }
        // reduce 4 K-slices within wave (lane bits 4,5)
#pragma unroll
        for (int off = 16; off <= 32; off <<= 1) {
#pragma unroll
            for (int c = 0; c < CPG; ++c) {
                acc[c].x += __shfl_xor(acc[c].x, off);
                acc[c].y += __shfl_xor(acc[c].y, off);
                acc[c].z += __shfl_xor(acc[c].z, off);
                acc[c].w += __shfl_xor(acc[c].w, off);
            }
        }
        if (lane < 16) {
#pragma unroll
            for (int c = 0; c < CPG; ++c)
                *(float4*)&part[wav][c * 64 + 4 * lane] = acc[c];
        }
        __syncthreads();
        if (t < 256) {  // t = ch*64 + col
            float s = 0.f;
#pragma unroll
            for (int w = 0; w < 16; ++w) s += part[w][t];
            msg_store(&s2z[(size_t)(g * CPG + (t >> 6)) * H2 + ZRC * b + (t & 63)], s);
        }
        xbar(gflag, b, ++ep);

        // ---- LN stats over full zr row + sigmoid; z full, rh full (replicated) ----
        float vz[4];
        float sum = 0.f, ssq = 0.f;
#pragma unroll
        for (int j = 0; j < 4; ++j) {
            float v = msg_load(&s2zc[lc + 256 * j]);
            vz[j] = v;
            sum += v;
            ssq += v * v;
        }
#pragma unroll
        for (int off = 1; off < 64; off <<= 1) {
            sum += __shfl_xor(sum, off);
            ssq += __shfl_xor(ssq, off);
        }
        if (lane == 0) {
            red[ch][2 * (wav & 3) + 0] = sum;
            red[ch][2 * (wav & 3) + 1] = ssq;
        }
        __syncthreads();
        {
            float sm = red[ch][0] + red[ch][2] + red[ch][4] + red[ch][6];
            float sq = red[ch][1] + red[ch][3] + red[ch][5] + red[ch][7];
            float m1 = sm * (1.f / H2);
            float var1 = fmaxf(sq * (1.f / H2) - m1 * m1, 0.f);
            float inv1 = 1.f / (sqrtf(var1 + EPSV) + EPSV);
#pragma unroll
            for (int j = 0; j < 4; ++j) {
                int c = lc + 256 * j;
                float s2ln = g1[c] * ((vz[j] - m1) * inv1) + b1[c];
                float pre = s1z[j] + s2ln;
                float sg = fminf(fmaxf(0.2f * pre + 0.5f, 0.f), 1.f);
                if (c < HDIM)
                    zT[ch][c] = sg;
                else
                    rhT[ch][c - HDIM] = sg * hT[ch][c - HDIM];
            }
        }
        __syncthreads();

        // ---- GEMV-B: (r*h) @ U[:, 1024+32b..+32) for 4 chains ----
        float4 accB[CPG];
#pragma unroll
        for (int c = 0; c < CPG; ++c) accB[c] = make_float4(0.f, 0.f, 0.f, 0.f);
#pragma unroll
        for (int kk = 0; kk < 4; ++kk) {
            const int k = kB + 128 * kk;
            float4 u = *(const float4*)(UB + (size_t)(128 * kk) * H3);
            float r0 = rhT[0][k], r1 = rhT[1][k], r2 = rhT[2][k], r3 = rhT[3][k];
            accB[0].x += r0 * u.x; accB[0].y += r0 * u.y; accB[0].z += r0 * u.z; accB[0].w += r0 * u.w;
            accB[1].x += r1 * u.x; accB[1].y += r1 * u.y; accB[1].z += r1 * u.z; accB[1].w += r1 * u.w;
            accB[2].x += r2 * u.x; accB[2].y += r2 * u.y; accB[2].z += r2 * u.z; accB[2].w += r2 * u.w;
            accB[3].x += r3 * u.x; accB[3].y += r3 * u.y; accB[3].z += r3 * u.z; accB[3].w += r3 * u.w;
        }
#pragma unroll
        for (int off = 8; off <= 32; off <<= 1) {
#pragma unroll
            for (int c = 0; c < CPG; ++c) {
                accB[c].x += __shfl_xor(accB[c].x, off);
                accB[c].y += __shfl_xor(accB[c].y, off);
                accB[c].z += __shfl_xor(accB[c].z, off);
                accB[c].w += __shfl_xor(accB[c].w, off);
            }
        }
        if (lane < 8) {
#pragma unroll
            for (int c = 0; c < CPG; ++c)
                *(float4*)&part[wav][c * 32 + 4 * lane] = accB[c];
        }
        __syncthreads();
        if (t < 128) {  // t = ch*32 + col
            float s = 0.f;
#pragma unroll
            for (int w = 0; w < 16; ++w) s += part[w][t];
            msg_store(&s2h[(size_t)(g * CPG + (t >> 5)) * HDIM + HCC * b + (t & 31)], s);
        }
        xbar(gflag, b, ++ep);

        // ---- LN stats over h-cand row + tanh + FULL replicated h update ----
        float vh[2];
        float sum2 = 0.f, ssq2 = 0.f;
#pragma unroll
        for (int j = 0; j < 2; ++j) {
            float v = msg_load(&s2hc[lc + 256 * j]);
            vh[j] = v;
            sum2 += v;
            ssq2 += v * v;
        }
#pragma unroll
        for (int off = 1; off < 64; off <<= 1) {
            sum2 += __shfl_xor(sum2, off);
            ssq2 += __shfl_xor(ssq2, off);
        }
        if (lane == 0) {
            red[ch][2 * (wav & 3) + 0] = sum2;
            red[ch][2 * (wav & 3) + 1] = ssq2;
        }
        __syncthreads();
        {
            float sm = red[ch][0] + red[ch][2] + red[ch][4] + red[ch][6];
            float sq = red[ch][1] + red[ch][3] + red[ch][5] + red[ch][7];
            float m2 = sm * (1.f / HDIM);
            float var2 = fmaxf(sq * (1.f / HDIM) - m2 * m2, 0.f);
            float inv2 = 1.f / (sqrtf(var2 + EPSV) + EPSV);
#pragma unroll
            for (int j = 0; j < 2; ++j) {
                int c = lc + 256 * j;
                float ln = g1[H2 + c] * ((vh[j] - m2) * inv2) + b1[H2 + c];
                float hc = tanhf(s1h[j] + ln);
                float hp = hT[ch][c];
                float z = zT[ch][c];
                float h_ = z * hp + (1.f - z) * hc;
                float hn = mk ? h_ : hp;
                hT[ch][c] = hn;
                if ((c >> 5) == b)  // own 32-col slice -> contiguous 128B burst
                    out[((size_t)gch * TSTEPS + step) * HDIM + c] = hn;
            }
        }
        __syncthreads();  // hT complete before next step's GEMV-A
    }
}

extern "C" void kernel_launch(void* const* d_in, const int* in_sizes, int n_in,
                              void* d_out, int out_size, void* d_ws, size_t ws_size,
                              hipStream_t stream) {
    const float* x      = (const float*)d_in[0];
    const int*   mask   = (const int*)d_in[1];
    const float* W_emb  = (const float*)d_in[2];
    const float* b_emb  = (const float*)d_in[3];
    const float* W      = (const float*)d_in[4];
    const float* U      = (const float*)d_in[5];
    const float* bias   = (const float*)d_in[6];
    const float* gammas = (const float*)d_in[7];
    const float* betas  = (const float*)d_in[8];
    float* out = (float*)d_out;

    const int M = BDIM * TSTEPS;  // 65536
    float* x_emb = (float*)d_ws;              // M x 512  (128 MB)
    float* s1    = x_emb + (size_t)M * HDIM;  // M x 1536 (384 MB)

    // scratch overlaid in x_emb region (dead after GEMM2)
    float* s2z = x_emb;                                     // 32x1024
    float* s2h = s2z + 32 * H2;                             // 32x512
    unsigned int* flags = (unsigned int*)(s2h + 32 * HDIM); // 128 x 32 uints

    // x_emb = x @ W_emb + b_emb
    sgemm<128, 128, 16, 8, 8><<<dim3(HDIM / 128, M / 128), 256, 0, stream>>>(
        x, W_emb, b_emb, x_emb, M, HDIM, DIN);
    // s1 = x_emb @ W  (raw)
    sgemm<128, 128, 16, 8, 8><<<dim3(H3 / 128, M / 128), 256, 0, stream>>>(
        x_emb, W, nullptr, s1, M, H3, HDIM);
    // s1 = LN0(s1 + bias) with gammas[0]/betas[0]  (h-independent, hoisted)
    ln0_kernel<<<M, 256, 0, stream>>>(s1, bias, gammas, betas);
    // zero barrier flags (ws re-poisoned 0xAA before every timed launch)
    hipMemsetAsync(flags, 0, NG * BPG * 32 * sizeof(unsigned int), stream);
    // persistent col-split scan, fence-free sc1 message passing
    scan_kernel<<<NG * BPG, 1024, 0, stream>>>(s1, U, gammas, betas, mask, out,
                                               s2z, s2h, flags);
}

// Round 6
// 30109.286 us; speedup vs baseline: 5.1185x; 1.0201x over previous
//
#include <hip/hip_runtime.h>
#include <hip/hip_bf16.h>
#include <math.h>

#define EPSV 1e-5f
#define BDIM 32
#define TSTEPS 2048
#define DIN 256
#define HDIM 512
#define H2 1024
#define H3 1536

#define NG 8      // chain groups
#define CPG 4     // chains per group (2 cohorts x 2)
#define BPG 16    // blocks per group
#define ZRC 64    // zr cols per block
#define HCC 32    // h-cand cols per block

// sc1 message passing: per-access agent coherence, no cache flushes.
__device__ __forceinline__ void msg_store(float* p, float v) {
    __hip_atomic_store(p, v, __ATOMIC_RELAXED, __HIP_MEMORY_SCOPE_AGENT);
}
__device__ __forceinline__ float msg_load(const float* p) {
    return __hip_atomic_load(p, __ATOMIC_RELAXED, __HIP_MEMORY_SCOPE_AGENT);
}

// ---------------- fp32 tiled GEMM: C = A(MxK) @ B(KxN) (+bias) ----------------
template <int BM, int BN, int BK, int TM, int TN>
__global__ __launch_bounds__(256) void sgemm(const float* __restrict__ A,
                                             const float* __restrict__ B,
                                             const float* __restrict__ bias,
                                             float* __restrict__ C,
                                             int M, int N, int K) {
    __shared__ float As[BK][BM + 4];
    __shared__ float Bs[BK][BN + 4];

    const int tid = threadIdx.x;
    const int bm = blockIdx.y * BM;
    const int bn = blockIdx.x * BN;

    const int tr = (tid >> 4) * TM;
    const int tc = (tid & 15) * TN;

    float acc[TM][TN];
#pragma unroll
    for (int i = 0; i < TM; ++i)
#pragma unroll
        for (int j = 0; j < TN; ++j) acc[i][j] = 0.f;

    for (int k0 = 0; k0 < K; k0 += BK) {
#pragma unroll
        for (int r = 0; r < 2; ++r) {
            int f = tid + r * 256;
            int arow = f >> 2;
            int acol = (f & 3) * 4;
            float4 v = *(const float4*)&A[(size_t)(bm + arow) * K + k0 + acol];
            As[acol + 0][arow] = v.x;
            As[acol + 1][arow] = v.y;
            As[acol + 2][arow] = v.z;
            As[acol + 3][arow] = v.w;
        }
#pragma unroll
        for (int r = 0; r < 2; ++r) {
            int f = tid + r * 256;
            int brow = f >> 5;
            int bcol = (f & 31) * 4;
            float4 v = *(const float4*)&B[(size_t)(k0 + brow) * N + bn + bcol];
            *(float4*)&Bs[brow][bcol] = v;
        }
        __syncthreads();
#pragma unroll
        for (int k = 0; k < BK; ++k) {
            float a[TM], b[TN];
            float4 a0 = *(const float4*)&As[k][tr];
            float4 a1 = *(const float4*)&As[k][tr + 4];
            a[0] = a0.x; a[1] = a0.y; a[2] = a0.z; a[3] = a0.w;
            a[4] = a1.x; a[5] = a1.y; a[6] = a1.z; a[7] = a1.w;
            float4 b0 = *(const float4*)&Bs[k][tc];
            float4 b1 = *(const float4*)&Bs[k][tc + 4];
            b[0] = b0.x; b[1] = b0.y; b[2] = b0.z; b[3] = b0.w;
            b[4] = b1.x; b[5] = b1.y; b[6] = b1.z; b[7] = b1.w;
#pragma unroll
            for (int i = 0; i < TM; ++i)
#pragma unroll
                for (int j = 0; j < TN; ++j) acc[i][j] += a[i] * b[j];
        }
        __syncthreads();
    }

#pragma unroll
    for (int i = 0; i < TM; ++i) {
        size_t row = (size_t)(bm + tr + i) * N + bn + tc;
#pragma unroll
        for (int j = 0; j < TN; j += 4) {
            float4 o;
            o.x = acc[i][j + 0];
            o.y = acc[i][j + 1];
            o.z = acc[i][j + 2];
            o.w = acc[i][j + 3];
            if (bias) {
                o.x += bias[bn + tc + j + 0];
                o.y += bias[bn + tc + j + 1];
                o.z += bias[bn + tc + j + 2];
                o.w += bias[bn + tc + j + 3];
            }
            *(float4*)&C[row + j] = o;
        }
    }
}

// ---------------- block-wide {sum, sumsq} reduction (256 threads) -------------
__device__ __forceinline__ void block_reduce2(float& a, float& b, float* red) {
#pragma unroll
    for (int off = 32; off > 0; off >>= 1) {
        a += __shfl_down(a, off);
        b += __shfl_down(b, off);
    }
    const int wid = threadIdx.x >> 6;
    __syncthreads();
    if ((threadIdx.x & 63) == 0) {
        red[wid] = a;
        red[4 + wid] = b;
    }
    __syncthreads();
    a = red[0] + red[1] + red[2] + red[3];
    b = red[4] + red[5] + red[6] + red[7];
}

// ---------------- LN0: in-place layernorm of s1 rows (+bias b) ----------------
__global__ __launch_bounds__(256) void ln0_kernel(float* __restrict__ s1,
                                                  const float* __restrict__ bvec,
                                                  const float* __restrict__ g0,
                                                  const float* __restrict__ b0) {
    const size_t row = blockIdx.x;
    float* p = s1 + row * H3;
    const int tid = threadIdx.x;
    __shared__ float red[8];
    float v[6];
    float sum = 0.f, ssq = 0.f;
#pragma unroll
    for (int j = 0; j < 6; ++j) {
        int k = tid + 256 * j;
        float x = p[k] + bvec[k];
        v[j] = x;
        sum += x;
        ssq += x * x;
    }
    block_reduce2(sum, ssq, red);
    float m = sum * (1.f / H3);
    float var = fmaxf(ssq * (1.f / H3) - m * m, 0.f);
    float inv = 1.f / (sqrtf(var + EPSV) + EPSV);
#pragma unroll
    for (int j = 0; j < 6; ++j) {
        int k = tid + 256 * j;
        p[k] = g0[k] * ((v[j] - m) * inv) + b0[k];
    }
}

// ---- split barrier: post (non-blocking publish) / wait (spin on 16 flags) ----
__device__ __forceinline__ void xpost(unsigned int* gflag, int b, unsigned int val) {
    asm volatile("s_waitcnt vmcnt(0)" ::: "memory");  // this wave's sc1 stores done
    __syncthreads();                                  // all waves drained
    if (threadIdx.x == 0)
        __hip_atomic_store(gflag + b * 32, val, __ATOMIC_RELAXED,
                           __HIP_MEMORY_SCOPE_AGENT);
}
__device__ __forceinline__ void xwait(const unsigned int* gflag, unsigned int target) {
    if (threadIdx.x < BPG) {
        while (__hip_atomic_load(gflag + threadIdx.x * 32, __ATOMIC_RELAXED,
                                 __HIP_MEMORY_SCOPE_AGENT) < target)
            __builtin_amdgcn_s_sleep(1);
    }
    asm volatile("" ::: "memory");
    __syncthreads();
}

// ---------------- persistent col-split scan, U-in-registers, 2 cohorts --------
// 128 blocks x 1024 thr. group g = blockIdx%8, b = blockIdx/8.
// Block b owns zr cols [64b,64b+64), h-cand cols [1024+32b,+32).
// Cohort q handles chains {2q, 2q+1}; pipeline hides barrier latency.
__global__ __launch_bounds__(1024) void scan_kernel(
    const float* __restrict__ s1,    // (32,2048,1536) pre-LN'd
    const float* __restrict__ U,     // (512,1536)
    const float* __restrict__ gam,   // (2,1536)
    const float* __restrict__ bet,   // (2,1536)
    const int* __restrict__ mask,    // (32,2048)
    float* __restrict__ out,         // (32,2048,512)
    float* __restrict__ s2z,         // (32,1024) publish
    float* __restrict__ s2h,         // (32,512)  publish
    unsigned int* __restrict__ flags)
{
    const int g = blockIdx.x & 7;
    const int b = blockIdx.x >> 3;
    const int t = threadIdx.x;
    const int wav = t >> 6;
    const int lane = t & 63;
    const int gbase = g * CPG;

    __shared__ float hT[CPG][HDIM];
    __shared__ float rhT[CPG][HDIM];
    __shared__ float part[2][16][128];
    __shared__ float red[16][2];

    for (int i = t; i < CPG * HDIM; i += 1024) (&hT[0][0])[i] = 0.f;

    unsigned int* gflag = flags + g * BPG * 32;

    // GEMV roles
    const int cA = t & 15;   // col-quad (A), k = kA + 64*kk
    const int kA = t >> 4;
    const int cB = t & 7;    // col-quad (B), k = kB + 128*kk
    const int kB = t >> 3;
    // elementwise roles: ci = chain-within-cohort, lz = col in [0,512)
    const int ci = t >> 9;
    const int lz = t & 511;

    // ---- U slice resident in registers (constant across all steps) ----
    float4 ua[8], ub[4];
    {
        const float* UA = U + (size_t)kA * H3 + ZRC * b + 4 * cA;
#pragma unroll
        for (int kk = 0; kk < 8; ++kk) ua[kk] = *(const float4*)(UA + (size_t)(64 * kk) * H3);
        const float* UB = U + (size_t)kB * H3 + H2 + HCC * b + 4 * cB;
#pragma unroll
        for (int kk = 0; kk < 4; ++kk) ub[kk] = *(const float4*)(UB + (size_t)(128 * kk) * H3);
    }
    // ---- per-thread gamma/beta in registers ----
    const float* g1 = gam + H3;
    const float* b1 = bet + H3;
    const float gz0 = g1[lz],        bz0 = b1[lz];
    const float gz1 = g1[lz + 512],  bz1 = b1[lz + 512];
    const float gh  = g1[H2 + lz],   bh  = b1[H2 + lz];

    const size_t chg0 = (size_t)(gbase + ci);       // cohort-0 global chain
    const size_t chg1 = (size_t)(gbase + 2 + ci);   // cohort-1 global chain
    const float* s1r0 = s1 + chg0 * TSTEPS * H3;
    const float* s1r1 = s1 + chg1 * TSTEPS * H3;
    const int* m0row = mask + chg0 * TSTEPS;
    const int* m1row = mask + chg1 * TSTEPS;
    float* outr0 = out + chg0 * TSTEPS * HDIM;
    float* outr1 = out + chg1 * TSTEPS * HDIM;

    __syncthreads();

    // GEMV-A(q) + reduce + publish partial zr cols
    auto gemv_pubA = [&](int q) {
        float4 a0 = make_float4(0.f, 0.f, 0.f, 0.f);
        float4 a1 = make_float4(0.f, 0.f, 0.f, 0.f);
#pragma unroll
        for (int kk = 0; kk < 8; ++kk) {
            const int k = kA + 64 * kk;
            const float h0 = hT[2 * q + 0][k];
            const float h1 = hT[2 * q + 1][k];
            a0.x += h0 * ua[kk].x; a0.y += h0 * ua[kk].y; a0.z += h0 * ua[kk].z; a0.w += h0 * ua[kk].w;
            a1.x += h1 * ua[kk].x; a1.y += h1 * ua[kk].y; a1.z += h1 * ua[kk].z; a1.w += h1 * ua[kk].w;
        }
#pragma unroll
        for (int off = 16; off <= 32; off <<= 1) {
            a0.x += __shfl_xor(a0.x, off); a0.y += __shfl_xor(a0.y, off);
            a0.z += __shfl_xor(a0.z, off); a0.w += __shfl_xor(a0.w, off);
            a1.x += __shfl_xor(a1.x, off); a1.y += __shfl_xor(a1.y, off);
            a1.z += __shfl_xor(a1.z, off); a1.w += __shfl_xor(a1.w, off);
        }
        if (lane < 16) {
            *(float4*)&part[q][wav][4 * lane] = a0;
            *(float4*)&part[q][wav][64 + 4 * lane] = a1;
        }
        __syncthreads();
        if (t < 128) {
            float s = 0.f;
#pragma unroll
            for (int w = 0; w < 16; ++w) s += part[q][w][t];
            msg_store(&s2z[(size_t)(gbase + 2 * q + (t >> 6)) * H2 + ZRC * b + (t & 63)], s);
        }
    };

    // GEMV-B(q) + reduce + publish partial h-cand cols
    auto gemv_pubB = [&](int q) {
        float4 a0 = make_float4(0.f, 0.f, 0.f, 0.f);
        float4 a1 = make_float4(0.f, 0.f, 0.f, 0.f);
#pragma unroll
        for (int kk = 0; kk < 4; ++kk) {
            const int k = kB + 128 * kk;
            const float r0 = rhT[2 * q + 0][k];
            const float r1 = rhT[2 * q + 1][k];
            a0.x += r0 * ub[kk].x; a0.y += r0 * ub[kk].y; a0.z += r0 * ub[kk].z; a0.w += r0 * ub[kk].w;
            a1.x += r1 * ub[kk].x; a1.y += r1 * ub[kk].y; a1.z += r1 * ub[kk].z; a1.w += r1 * ub[kk].w;
        }
#pragma unroll
        for (int off = 8; off <= 32; off <<= 1) {
            a0.x += __shfl_xor(a0.x, off); a0.y += __shfl_xor(a0.y, off);
            a0.z += __shfl_xor(a0.z, off); a0.w += __shfl_xor(a0.w, off);
            a1.x += __shfl_xor(a1.x, off); a1.y += __shfl_xor(a1.y, off);
            a1.z += __shfl_xor(a1.z, off); a1.w += __shfl_xor(a1.w, off);
        }
        if (lane < 8) {
            *(float4*)&part[q][wav][4 * lane] = a0;
            *(float4*)&part[q][wav][32 + 4 * lane] = a1;
        }
        __syncthreads();
        if (t < 64) {
            float s = 0.f;
#pragma unroll
            for (int w = 0; w < 16; ++w) s += part[q][w][t];
            msg_store(&s2h[(size_t)(gbase + 2 * q + (t >> 5)) * HDIM + HCC * b + (t & 31)], s);
        }
    };

    // consume zr row (cohort q): LN + hard-sigmoid; z -> reg, rh -> LDS
    auto consume_Z = [&](int q, float s1a, float s1b, float& zout) {
        const int chq = 2 * q + ci;
        const float* p = s2z + (size_t)(gbase + chq) * H2;
        float v0 = msg_load(&p[lz]);
        float v1 = msg_load(&p[lz + 512]);
        float sum = v0 + v1, ssq = v0 * v0 + v1 * v1;
#pragma unroll
        for (int off = 1; off < 64; off <<= 1) {
            sum += __shfl_xor(sum, off);
            ssq += __shfl_xor(ssq, off);
        }
        if (lane == 0) { red[wav][0] = sum; red[wav][1] = ssq; }
        __syncthreads();
        float sm = 0.f, sq = 0.f;
#pragma unroll
        for (int j = 0; j < 8; ++j) { sm += red[ci * 8 + j][0]; sq += red[ci * 8 + j][1]; }
        float m = sm * (1.f / H2);
        float var = fmaxf(sq * (1.f / H2) - m * m, 0.f);
        float inv = 1.f / (sqrtf(var + EPSV) + EPSV);
        float pz = s1a + gz0 * ((v0 - m) * inv) + bz0;
        zout = fminf(fmaxf(0.2f * pz + 0.5f, 0.f), 1.f);
        float pr = s1b + gz1 * ((v1 - m) * inv) + bz1;
        float r = fminf(fmaxf(0.2f * pr + 0.5f, 0.f), 1.f);
        rhT[chq][lz] = r * hT[chq][lz];
    };

    // consume h-cand row (cohort q): LN + tanh + gated h update + out write
    auto consume_H = [&](int q, float s1hv, float z, int mkv, float* outrow, int step) {
        const int chq = 2 * q + ci;
        float v = msg_load(&s2h[(size_t)(gbase + chq) * HDIM + lz]);
        float sum = v, ssq = v * v;
#pragma unroll
        for (int off = 1; off < 64; off <<= 1) {
            sum += __shfl_xor(sum, off);
            ssq += __shfl_xor(ssq, off);
        }
        if (lane == 0) { red[wav][0] = sum; red[wav][1] = ssq; }
        __syncthreads();
        float sm = 0.f, sq = 0.f;
#pragma unroll
        for (int j = 0; j < 8; ++j) { sm += red[ci * 8 + j][0]; sq += red[ci * 8 + j][1]; }
        float m = sm * (1.f / HDIM);
        float var = fmaxf(sq * (1.f / HDIM) - m * m, 0.f);
        float inv = 1.f / (sqrtf(var + EPSV) + EPSV);
        float ln = gh * ((v - m) * inv) + bh;
        float hc = tanhf(s1hv + ln);
        float hp = hT[chq][lz];
        float h_ = z * hp + (1.f - z) * hc;
        float hn = mkv ? h_ : hp;
        hT[chq][lz] = hn;
        if ((lz >> 5) == b)
            outrow[(size_t)step * HDIM + lz] = hn;
    };

    for (int step = 0; step < TSTEPS; ++step) {
        const unsigned int e0 = 4u * (unsigned int)step;
        // prefetch this step's s1 slices + masks (hidden under GEMV-A compute)
        const float* p0 = s1r0 + (size_t)step * H3;
        const float* p1 = s1r1 + (size_t)step * H3;
        float s1a0 = p0[lz], s1b0 = p0[lz + 512], s1h0 = p0[H2 + lz];
        float s1a1 = p1[lz], s1b1 = p1[lz + 512], s1h1 = p1[H2 + lz];
        const int mk0 = m0row[step];
        const int mk1 = m1row[step];

        gemv_pubA(0); xpost(gflag, b, e0 + 1);
        gemv_pubA(1); xpost(gflag, b, e0 + 2);

        xwait(gflag, e0 + 1);
        float z0; consume_Z(0, s1a0, s1b0, z0);
        __syncthreads();                       // rhT[0..1] ready
        gemv_pubB(0); xpost(gflag, b, e0 + 3);

        xwait(gflag, e0 + 2);
        float z1; consume_Z(1, s1a1, s1b1, z1);
        __syncthreads();                       // rhT[2..3] ready
        gemv_pubB(1); xpost(gflag, b, e0 + 4);

        xwait(gflag, e0 + 3);
        consume_H(0, s1h0, z0, mk0, outr0, step);
        xwait(gflag, e0 + 4);
        consume_H(1, s1h1, z1, mk1, outr1, step);
        __syncthreads();                       // hT complete before next step
    }
}

extern "C" void kernel_launch(void* const* d_in, const int* in_sizes, int n_in,
                              void* d_out, int out_size, void* d_ws, size_t ws_size,
                              hipStream_t stream) {
    const float* x      = (const float*)d_in[0];
    const int*   mask   = (const int*)d_in[1];
    const float* W_emb  = (const float*)d_in[2];
    const float* b_emb  = (const float*)d_in[3];
    const float* W      = (const float*)d_in[4];
    const float* U      = (const float*)d_in[5];
    const float* bias   = (const float*)d_in[6];
    const float* gammas = (const float*)d_in[7];
    const float* betas  = (const float*)d_in[8];
    float* out = (float*)d_out;

    const int M = BDIM * TSTEPS;  // 65536
    float* x_emb = (float*)d_ws;              // M x 512  (128 MB)
    float* s1    = x_emb + (size_t)M * HDIM;  // M x 1536 (384 MB)

    // scratch overlaid in x_emb region (dead after GEMM2)
    float* s2z = x_emb;                                     // 32x1024
    float* s2h = s2z + 32 * H2;                             // 32x512
    unsigned int* flags = (unsigned int*)(s2h + 32 * HDIM); // 128 x 32 uints

    // x_emb = x @ W_emb + b_emb
    sgemm<128, 128, 16, 8, 8><<<dim3(HDIM / 128, M / 128), 256, 0, stream>>>(
        x, W_emb, b_emb, x_emb, M, HDIM, DIN);
    // s1 = x_emb @ W  (raw)
    sgemm<128, 128, 16, 8, 8><<<dim3(H3 / 128, M / 128), 256, 0, stream>>>(
        x_emb, W, nullptr, s1, M, H3, HDIM);
    // s1 = LN0(s1 + bias) with gammas[0]/betas[0]  (h-independent, hoisted)
    ln0_kernel<<<M, 256, 0, stream>>>(s1, bias, gammas, betas);
    // zero barrier flags (ws re-poisoned 0xAA before every timed launch)
    hipMemsetAsync(flags, 0, NG * BPG * 32 * sizeof(unsigned int), stream);
    // persistent scan: U in registers, 2-cohort pipelined barriers
    scan_kernel<<<NG * BPG, 1024, 0, stream>>>(s1, U, gammas, betas, mask, out,
                                               s2z, s2h, flags);
}

// Round 9
// 23426.410 us; speedup vs baseline: 6.5786x; 1.2853x over previous
//
#include <hip/hip_runtime.h>
#include <hip/hip_bf16.h>
#include <math.h>

#define EPSV 1e-5f
#define BDIM 32
#define TSTEPS 2048
#define DIN 256
#define HDIM 512
#define H2 1024
#define H3 1536

#define NG 8      // chain groups
#define CPG 4     // chains per group
#define BPG 16    // blocks per group
#define ZRC 64    // zr cols per block
#define HCC 32    // h-cand cols per block

// sc1 message passing: per-access agent coherence, no cache flushes.
__device__ __forceinline__ void msg_store(float* p, float v) {
    __hip_atomic_store(p, v, __ATOMIC_RELAXED, __HIP_MEMORY_SCOPE_AGENT);
}
__device__ __forceinline__ float msg_load(const float* p) {
    return __hip_atomic_load(p, __ATOMIC_RELAXED, __HIP_MEMORY_SCOPE_AGENT);
}
__device__ __forceinline__ float hsig(float x) {
    return fminf(fmaxf(0.2f * x + 0.5f, 0.f), 1.f);
}

// ---------------- fp32 tiled GEMM: C = A(MxK) @ B(KxN) (+bias) ----------------
template <int BM, int BN, int BK, int TM, int TN>
__global__ __launch_bounds__(256) void sgemm(const float* __restrict__ A,
                                             const float* __restrict__ B,
                                             const float* __restrict__ bias,
                                             float* __restrict__ C,
                                             int M, int N, int K) {
    __shared__ float As[BK][BM + 4];
    __shared__ float Bs[BK][BN + 4];

    const int tid = threadIdx.x;
    const int bm = blockIdx.y * BM;
    const int bn = blockIdx.x * BN;

    const int tr = (tid >> 4) * TM;
    const int tc = (tid & 15) * TN;

    float acc[TM][TN];
#pragma unroll
    for (int i = 0; i < TM; ++i)
#pragma unroll
        for (int j = 0; j < TN; ++j) acc[i][j] = 0.f;

    for (int k0 = 0; k0 < K; k0 += BK) {
#pragma unroll
        for (int r = 0; r < 2; ++r) {
            int f = tid + r * 256;
            int arow = f >> 2;
            int acol = (f & 3) * 4;
            float4 v = *(const float4*)&A[(size_t)(bm + arow) * K + k0 + acol];
            As[acol + 0][arow] = v.x;
            As[acol + 1][arow] = v.y;
            As[acol + 2][arow] = v.z;
            As[acol + 3][arow] = v.w;
        }
#pragma unroll
        for (int r = 0; r < 2; ++r) {
            int f = tid + r * 256;
            int brow = f >> 5;
            int bcol = (f & 31) * 4;
            float4 v = *(const float4*)&B[(size_t)(k0 + brow) * N + bn + bcol];
            *(float4*)&Bs[brow][bcol] = v;
        }
        __syncthreads();
#pragma unroll
        for (int k = 0; k < BK; ++k) {
            float a[TM], b[TN];
            float4 a0 = *(const float4*)&As[k][tr];
            float4 a1 = *(const float4*)&As[k][tr + 4];
            a[0] = a0.x; a[1] = a0.y; a[2] = a0.z; a[3] = a0.w;
            a[4] = a1.x; a[5] = a1.y; a[6] = a1.z; a[7] = a1.w;
            float4 b0 = *(const float4*)&Bs[k][tc];
            float4 b1 = *(const float4*)&Bs[k][tc + 4];
            b[0] = b0.x; b[1] = b0.y; b[2] = b0.z; b[3] = b0.w;
            b[4] = b1.x; b[5] = b1.y; b[6] = b1.z; b[7] = b1.w;
#pragma unroll
            for (int i = 0; i < TM; ++i)
#pragma unroll
                for (int j = 0; j < TN; ++j) acc[i][j] += a[i] * b[j];
        }
        __syncthreads();
    }

#pragma unroll
    for (int i = 0; i < TM; ++i) {
        size_t row = (size_t)(bm + tr + i) * N + bn + tc;
#pragma unroll
        for (int j = 0; j < TN; j += 4) {
            float4 o;
            o.x = acc[i][j + 0];
            o.y = acc[i][j + 1];
            o.z = acc[i][j + 2];
            o.w = acc[i][j + 3];
            if (bias) {
                o.x += bias[bn + tc + j + 0];
                o.y += bias[bn + tc + j + 1];
                o.z += bias[bn + tc + j + 2];
                o.w += bias[bn + tc + j + 3];
            }
            *(float4*)&C[row + j] = o;
        }
    }
}

// ---------------- block-wide {sum, sumsq} reduction (256 threads) -------------
__device__ __forceinline__ void block_reduce2(float& a, float& b, float* red) {
#pragma unroll
    for (int off = 32; off > 0; off >>= 1) {
        a += __shfl_down(a, off);
        b += __shfl_down(b, off);
    }
    const int wid = threadIdx.x >> 6;
    __syncthreads();
    if ((threadIdx.x & 63) == 0) {
        red[wid] = a;
        red[4 + wid] = b;
    }
    __syncthreads();
    a = red[0] + red[1] + red[2] + red[3];
    b = red[4] + red[5] + red[6] + red[7];
}

// ---------------- LN0: in-place layernorm of s1 rows (+bias b) ----------------
__global__ __launch_bounds__(256) void ln0_kernel(float* __restrict__ s1,
                                                  const float* __restrict__ bvec,
                                                  const float* __restrict__ g0,
                                                  const float* __restrict__ b0) {
    const size_t row = blockIdx.x;
    float* p = s1 + row * H3;
    const int tid = threadIdx.x;
    __shared__ float red[8];
    float v[6];
    float sum = 0.f, ssq = 0.f;
#pragma unroll
    for (int j = 0; j < 6; ++j) {
        int k = tid + 256 * j;
        float x = p[k] + bvec[k];
        v[j] = x;
        sum += x;
        ssq += x * x;
    }
    block_reduce2(sum, ssq, red);
    float m = sum * (1.f / H3);
    float var = fmaxf(ssq * (1.f / H3) - m * m, 0.f);
    float inv = 1.f / (sqrtf(var + EPSV) + EPSV);
#pragma unroll
    for (int j = 0; j < 6; ++j) {
        int k = tid + 256 * j;
        p[k] = g0[k] * ((v[j] - m) * inv) + b0[k];
    }
}

// ---- split barrier: post (non-blocking publish) / wait (spin on 16 flags) ----
__device__ __forceinline__ void xpost(unsigned int* gflag, int bb, unsigned int val) {
    asm volatile("s_waitcnt vmcnt(0)" ::: "memory");  // payload stores visible
    __syncthreads();                                  // all waves drained
    if (threadIdx.x == 0)
        __hip_atomic_store(gflag + bb * 32, val, __ATOMIC_RELAXED,
                           __HIP_MEMORY_SCOPE_AGENT);
}
__device__ __forceinline__ void xwait(const unsigned int* gflag, unsigned int target) {
    if (threadIdx.x < BPG) {
        while (__hip_atomic_load(gflag + threadIdx.x * 32, __ATOMIC_RELAXED,
                                 __HIP_MEMORY_SCOPE_AGENT) < target)
            __builtin_amdgcn_s_sleep(1);
    }
    asm volatile("" ::: "memory");
    __syncthreads();
}

// ---------------- persistent col-split scan, U truly in registers -------------
// 128 blocks x 512 thr. group g = blockIdx%8, bb = blockIdx/8.
// Block bb owns zr cols [64bb,+64), h-cand cols [1024+32bb,+32).
// 2 epochs/step: post A-publish, post B-publish. h update fully replicated.
__global__ __launch_bounds__(512, 2) void scan_kernel(
    const float* __restrict__ s1,    // (32,2048,1536) pre-LN'd
    const float* __restrict__ U,     // (512,1536)
    const float* __restrict__ gam,   // (2,1536)
    const float* __restrict__ bet,   // (2,1536)
    const int* __restrict__ mask,    // (32,2048)
    float* __restrict__ out,         // (32,2048,512)
    float* __restrict__ s2z,         // (32,1024) publish
    float* __restrict__ s2h,         // (32,512)  publish
    unsigned int* __restrict__ flags)
{
    const int g = blockIdx.x & 7;
    const int bb = blockIdx.x >> 3;
    const int t = threadIdx.x;
    const int wav = t >> 6;
    const int lane = t & 63;
    const int gbase = g * CPG;
    const int lz = t;  // 0..511

    __shared__ float hT[CPG][HDIM];
    __shared__ float rhT[CPG][HDIM];
    __shared__ float part[8][CPG][64];
    __shared__ float red[8][8];

    for (int i = t; i < CPG * HDIM; i += 512) (&hT[0][0])[i] = 0.f;

    unsigned int* gflag = flags + g * BPG * 32;

    // GEMV roles
    const int cA = t & 15, kA = t >> 4;  // 16 col-quads, 32 K-splits; k=kA+32*kk
    const int cB = t & 7,  kB = t >> 3;  // 8 col-quads, 64 K-splits; k=kB+64*kk

    // ---- U slice resident in registers (96 VGPRs; cap raised to 256) ----
    float4 ua[16], ub[8];
    {
        const float* UA = U + (size_t)kA * H3 + ZRC * bb + 4 * cA;
#pragma unroll
        for (int kk = 0; kk < 16; ++kk)
            ua[kk] = *(const float4*)(UA + (size_t)(32 * kk) * H3);
        const float* UB = U + (size_t)kB * H3 + H2 + HCC * bb + 4 * cB;
#pragma unroll
        for (int kk = 0; kk < 8; ++kk)
            ub[kk] = *(const float4*)(UB + (size_t)(64 * kk) * H3);
    }
    const float* g1 = gam + H3;
    const float* b1 = bet + H3;
    const float gz0 = g1[lz], bz0 = b1[lz];
    const float gz1 = g1[lz + 512], bz1 = b1[lz + 512];
    const float gh = g1[H2 + lz], bh = b1[H2 + lz];

    const float* s1p[CPG];
    const int* mp[CPG];
    float* op[CPG];
#pragma unroll
    for (int c = 0; c < CPG; ++c) {
        const size_t chg = (size_t)(gbase + c);
        s1p[c] = s1 + chg * TSTEPS * H3;
        mp[c] = mask + chg * TSTEPS;
        op[c] = out + chg * TSTEPS * HDIM + lz;
    }
    float s1a[CPG], s1b[CPG], s1h[CPG];
    int mk[CPG];
#pragma unroll
    for (int c = 0; c < CPG; ++c) {
        s1a[c] = s1p[c][lz];
        s1b[c] = s1p[c][lz + 512];
        s1h[c] = s1p[c][H2 + lz];
        mk[c] = mp[c][0];
    }
    __syncthreads();

    for (int step = 0; step < TSTEPS; ++step) {
        const unsigned int e0 = 2u * (unsigned int)step;

        // ===== GEMV-A: h @ U_zr slice, all 4 chains, pure register FMA =====
        float4 acc0 = make_float4(0.f, 0.f, 0.f, 0.f);
        float4 acc1 = make_float4(0.f, 0.f, 0.f, 0.f);
        float4 acc2 = make_float4(0.f, 0.f, 0.f, 0.f);
        float4 acc3 = make_float4(0.f, 0.f, 0.f, 0.f);
#pragma unroll
        for (int kk = 0; kk < 16; ++kk) {
            const int k = kA + 32 * kk;
            const float h0 = hT[0][k], h1 = hT[1][k], h2 = hT[2][k], h3 = hT[3][k];
            const float4 u = ua[kk];
            acc0.x += h0 * u.x; acc0.y += h0 * u.y; acc0.z += h0 * u.z; acc0.w += h0 * u.w;
            acc1.x += h1 * u.x; acc1.y += h1 * u.y; acc1.z += h1 * u.z; acc1.w += h1 * u.w;
            acc2.x += h2 * u.x; acc2.y += h2 * u.y; acc2.z += h2 * u.z; acc2.w += h2 * u.w;
            acc3.x += h3 * u.x; acc3.y += h3 * u.y; acc3.z += h3 * u.z; acc3.w += h3 * u.w;
        }
#pragma unroll
        for (int off = 16; off <= 32; off <<= 1) {
            acc0.x += __shfl_xor(acc0.x, off); acc0.y += __shfl_xor(acc0.y, off);
            acc0.z += __shfl_xor(acc0.z, off); acc0.w += __shfl_xor(acc0.w, off);
            acc1.x += __shfl_xor(acc1.x, off); acc1.y += __shfl_xor(acc1.y, off);
            acc1.z += __shfl_xor(acc1.z, off); acc1.w += __shfl_xor(acc1.w, off);
            acc2.x += __shfl_xor(acc2.x, off); acc2.y += __shfl_xor(acc2.y, off);
            acc2.z += __shfl_xor(acc2.z, off); acc2.w += __shfl_xor(acc2.w, off);
            acc3.x += __shfl_xor(acc3.x, off); acc3.y += __shfl_xor(acc3.y, off);
            acc3.z += __shfl_xor(acc3.z, off); acc3.w += __shfl_xor(acc3.w, off);
        }
        if (lane < 16) {
            *(float4*)&part[wav][0][4 * lane] = acc0;
            *(float4*)&part[wav][1][4 * lane] = acc1;
            *(float4*)&part[wav][2][4 * lane] = acc2;
            *(float4*)&part[wav][3][4 * lane] = acc3;
        }
        __syncthreads();
        if (t < 256) {  // 4 chains x 64 cols
            const int c = t >> 6, col = t & 63;
            float s = 0.f;
#pragma unroll
            for (int w = 0; w < 8; ++w) s += part[w][c][col];
            msg_store(&s2z[(size_t)(gbase + c) * H2 + ZRC * bb + col], s);
        }
        xpost(gflag, bb, e0 + 1);

        // ---- prefetch next step's s1/mask (drained only at NEXT xpost) ----
        float na[CPG], nb[CPG], nh[CPG];
        int nm[CPG];
        if (step + 1 < TSTEPS) {
#pragma unroll
            for (int c = 0; c < CPG; ++c) {
                const float* p = s1p[c] + (size_t)(step + 1) * H3;
                na[c] = p[lz]; nb[c] = p[lz + 512]; nh[c] = p[H2 + lz];
                nm[c] = mp[c][step + 1];
            }
        }

        xwait(gflag, e0 + 1);

        // ===== consume zr: batched stats for 4 chains =====
        float v0[CPG], v1[CPG];
#pragma unroll
        for (int c = 0; c < CPG; ++c) {
            const float* p = s2z + (size_t)(gbase + c) * H2;
            v0[c] = msg_load(&p[lz]);
            v1[c] = msg_load(&p[lz + 512]);
        }
        float sum[CPG], ssq[CPG];
#pragma unroll
        for (int c = 0; c < CPG; ++c) {
            sum[c] = v0[c] + v1[c];
            ssq[c] = v0[c] * v0[c] + v1[c] * v1[c];
        }
#pragma unroll
        for (int off = 1; off < 64; off <<= 1) {
#pragma unroll
            for (int c = 0; c < CPG; ++c) {
                sum[c] += __shfl_xor(sum[c], off);
                ssq[c] += __shfl_xor(ssq[c], off);
            }
        }
        if (lane == 0) {
#pragma unroll
            for (int c = 0; c < CPG; ++c) {
                red[wav][2 * c] = sum[c];
                red[wav][2 * c + 1] = ssq[c];
            }
        }
        __syncthreads();
        float zr[CPG];
#pragma unroll
        for (int c = 0; c < CPG; ++c) {
            float sm = 0.f, sq = 0.f;
#pragma unroll
            for (int w = 0; w < 8; ++w) { sm += red[w][2 * c]; sq += red[w][2 * c + 1]; }
            const float m = sm * (1.f / H2);
            const float var = fmaxf(sq * (1.f / H2) - m * m, 0.f);
            const float inv = 1.f / (sqrtf(var + EPSV) + EPSV);
            zr[c] = hsig(s1a[c] + gz0 * ((v0[c] - m) * inv) + bz0);
            const float r = hsig(s1b[c] + gz1 * ((v1[c] - m) * inv) + bz1);
            rhT[c][lz] = r * hT[c][lz];
        }
        __syncthreads();  // rhT ready

        // ===== GEMV-B: (r*h) @ U_h slice, all 4 chains =====
        float4 bc0 = make_float4(0.f, 0.f, 0.f, 0.f);
        float4 bc1 = make_float4(0.f, 0.f, 0.f, 0.f);
        float4 bc2 = make_float4(0.f, 0.f, 0.f, 0.f);
        float4 bc3 = make_float4(0.f, 0.f, 0.f, 0.f);
#pragma unroll
        for (int kk = 0; kk < 8; ++kk) {
            const int k = kB + 64 * kk;
            const float r0 = rhT[0][k], r1 = rhT[1][k], r2 = rhT[2][k], r3 = rhT[3][k];
            const float4 u = ub[kk];
            bc0.x += r0 * u.x; bc0.y += r0 * u.y; bc0.z += r0 * u.z; bc0.w += r0 * u.w;
            bc1.x += r1 * u.x; bc1.y += r1 * u.y; bc1.z += r1 * u.z; bc1.w += r1 * u.w;
            bc2.x += r2 * u.x; bc2.y += r2 * u.y; bc2.z += r2 * u.z; bc2.w += r2 * u.w;
            bc3.x += r3 * u.x; bc3.y += r3 * u.y; bc3.z += r3 * u.z; bc3.w += r3 * u.w;
        }
#pragma unroll
        for (int off = 8; off <= 32; off <<= 1) {
            bc0.x += __shfl_xor(bc0.x, off); bc0.y += __shfl_xor(bc0.y, off);
            bc0.z += __shfl_xor(bc0.z, off); bc0.w += __shfl_xor(bc0.w, off);
            bc1.x += __shfl_xor(bc1.x, off); bc1.y += __shfl_xor(bc1.y, off);
            bc1.z += __shfl_xor(bc1.z, off); bc1.w += __shfl_xor(bc1.w, off);
            bc2.x += __shfl_xor(bc2.x, off); bc2.y += __shfl_xor(bc2.y, off);
            bc2.z += __shfl_xor(bc2.z, off); bc2.w += __shfl_xor(bc2.w, off);
            bc3.x += __shfl_xor(bc3.x, off); bc3.y += __shfl_xor(bc3.y, off);
            bc3.z += __shfl_xor(bc3.z, off); bc3.w += __shfl_xor(bc3.w, off);
        }
        if (lane < 8) {
            *(float4*)&part[wav][0][4 * lane] = bc0;
            *(float4*)&part[wav][1][4 * lane] = bc1;
            *(float4*)&part[wav][2][4 * lane] = bc2;
            *(float4*)&part[wav][3][4 * lane] = bc3;
        }
        __syncthreads();
        if (t < 128) {  // 4 chains x 32 cols
            const int c = t >> 5, col = t & 31;
            float s = 0.f;
#pragma unroll
            for (int w = 0; w < 8; ++w) s += part[w][c][col];
            msg_store(&s2h[(size_t)(gbase + c) * HDIM + HCC * bb + col], s);
        }
        xpost(gflag, bb, e0 + 2);
        xwait(gflag, e0 + 2);

        // ===== consume h-cand: batched stats + full replicated h update =====
        float hv[CPG];
#pragma unroll
        for (int c = 0; c < CPG; ++c)
            hv[c] = msg_load(&s2h[(size_t)(gbase + c) * HDIM + lz]);
        float sum2[CPG], ssq2[CPG];
#pragma unroll
        for (int c = 0; c < CPG; ++c) { sum2[c] = hv[c]; ssq2[c] = hv[c] * hv[c]; }
#pragma unroll
        for (int off = 1; off < 64; off <<= 1) {
#pragma unroll
            for (int c = 0; c < CPG; ++c) {
                sum2[c] += __shfl_xor(sum2[c], off);
                ssq2[c] += __shfl_xor(ssq2[c], off);
            }
        }
        if (lane == 0) {
#pragma unroll
            for (int c = 0; c < CPG; ++c) {
                red[wav][2 * c] = sum2[c];
                red[wav][2 * c + 1] = ssq2[c];
            }
        }
        __syncthreads();
#pragma unroll
        for (int c = 0; c < CPG; ++c) {
            float sm = 0.f, sq = 0.f;
#pragma unroll
            for (int w = 0; w < 8; ++w) { sm += red[w][2 * c]; sq += red[w][2 * c + 1]; }
            const float m = sm * (1.f / HDIM);
            const float var = fmaxf(sq * (1.f / HDIM) - m * m, 0.f);
            const float inv = 1.f / (sqrtf(var + EPSV) + EPSV);
            const float ln = gh * ((hv[c] - m) * inv) + bh;
            const float hc = tanhf(s1h[c] + ln);
            const float hp = hT[c][lz];
            const float h_ = zr[c] * hp + (1.f - zr[c]) * hc;
            const float hn = mk[c] ? h_ : hp;
            hT[c][lz] = hn;
            if ((lz >> 5) == bb) op[c][(size_t)step * HDIM] = hn;
        }
        __syncthreads();  // hT complete before next step's GEMV-A

        // rotate prefetched s1/mask
#pragma unroll
        for (int c = 0; c < CPG; ++c) {
            s1a[c] = na[c]; s1b[c] = nb[c]; s1h[c] = nh[c]; mk[c] = nm[c];
        }
    }
}

extern "C" void kernel_launch(void* const* d_in, const int* in_sizes, int n_in,
                              void* d_out, int out_size, void* d_ws, size_t ws_size,
                              hipStream_t stream) {
    const float* x      = (const float*)d_in[0];
    const int*   mask   = (const int*)d_in[1];
    const float* W_emb  = (const float*)d_in[2];
    const float* b_emb  = (const float*)d_in[3];
    const float* W      = (const float*)d_in[4];
    const float* U      = (const float*)d_in[5];
    const float* bias   = (const float*)d_in[6];
    const float* gammas = (const float*)d_in[7];
    const float* betas  = (const float*)d_in[8];
    float* out = (float*)d_out;

    const int M = BDIM * TSTEPS;  // 65536
    float* x_emb = (float*)d_ws;              // M x 512  (128 MB)
    float* s1    = x_emb + (size_t)M * HDIM;  // M x 1536 (384 MB)

    // scratch overlaid in x_emb region (dead after GEMM2)
    float* s2z = x_emb;                                     // 32x1024
    float* s2h = s2z + 32 * H2;                             // 32x512
    unsigned int* flags = (unsigned int*)(s2h + 32 * HDIM); // 128 x 32 uints

    // x_emb = x @ W_emb + b_emb
    sgemm<128, 128, 16, 8, 8><<<dim3(HDIM / 128, M / 128), 256, 0, stream>>>(
        x, W_emb, b_emb, x_emb, M, HDIM, DIN);
    // s1 = x_emb @ W  (raw)
    sgemm<128, 128, 16, 8, 8><<<dim3(H3 / 128, M / 128), 256, 0, stream>>>(
        x_emb, W, nullptr, s1, M, H3, HDIM);
    // s1 = LN0(s1 + bias) with gammas[0]/betas[0]  (h-independent, hoisted)
    ln0_kernel<<<M, 256, 0, stream>>>(s1, bias, gammas, betas);
    // zero barrier flags (ws re-poisoned 0xAA before every timed launch)
    hipMemsetAsync(flags, 0, NG * BPG * 32 * sizeof(unsigned int), stream);
    // persistent scan: U truly in registers (512thr, VGPR cap 256), 2 epochs/step
    scan_kernel<<<NG * BPG, 512, 0, stream>>>(s1, U, gammas, betas, mask, out,
                                              s2z, s2h, flags);
}